// Round 1
// baseline (685.873 us; speedup 1.0000x reference)
//
#include <hip/hip_runtime.h>
#include <stdint.h>

#define BTOT   4096
#define NGRP   8
#define DMODEL 1024
#define HIDDEN 2048
#define ABIN   256

typedef short bf16x8 __attribute__((ext_vector_type(8)));
typedef short bf16x4 __attribute__((ext_vector_type(4)));
typedef float f32x4  __attribute__((ext_vector_type(4)));

__device__ __forceinline__ ushort f2bf(float f) {
    union { float f; uint32_t u; } v; v.f = f;
    return (ushort)((v.u + 0x7FFFu + ((v.u >> 16) & 1u)) >> 16);
}

// MODE 0: A = x (f32, row stride NGRP*DMODEL), B = W1[n] (K=1024 -> N=2048),
//         out = h (bf16, relu, layout [n][CH][HIDDEN])
// MODE 1: A = h (bf16, row stride HIDDEN),     B = W2[n] (K=2048 -> N=256),
//         out = final (f32, layout [b][n][ABIN])
template<int MODE>
__global__ __launch_bounds__(256, 2)
void mlp_gemm(const void* __restrict__ Ap, const float* __restrict__ Wp,
              const float* __restrict__ biasp, void* __restrict__ outp,
              int CH, int cb)
{
    constexpr int K    = (MODE == 0) ? DMODEL : HIDDEN;
    constexpr int NDIM = (MODE == 0) ? HIDDEN : ABIN;
    constexpr int NT   = NDIM / 128;
    constexpr int LDP  = 40;              // padded LDS row stride (bf16 elems) = 80 B

    const int n   = blockIdx.y;
    const int mt  = blockIdx.x / NT;
    const int nt  = blockIdx.x % NT;
    const int m0  = mt * 128;             // row offset within chunk
    const int bn0 = nt * 128;             // col offset

    const int t  = threadIdx.x;
    const int l  = t & 63;
    const int w  = t >> 6;
    const int wr = w >> 1, wc = w & 1;    // wave -> 64x64 sub-tile
    const int lq = l >> 4, lr = l & 15;

    __shared__ __align__(16) ushort Al[128 * LDP];
    __shared__ __align__(16) ushort Bl[128 * LDP];

    const float* Wg = Wp + (size_t)n * K * NDIM;

    f32x4 acc[4][4];
#pragma unroll
    for (int i = 0; i < 4; i++)
#pragma unroll
        for (int j = 0; j < 4; j++) acc[i][j] = (f32x4){0.f, 0.f, 0.f, 0.f};

    // B staging assignment: thread covers k = kb*4..+3, n-cols = nb*4..+3
    const int kb = t >> 5;                // 0..7
    const int nb = t & 31;                // 0..31

    for (int kt = 0; kt < K / 32; ++kt) {
        const int k0 = kt * 32;
        __syncthreads();

        // ---- stage A tile [128 rows][32 k] -> Al (bf16, padded rows) ----
        if constexpr (MODE == 0) {
            const float* A = (const float*)Ap;
#pragma unroll
            for (int i = 0; i < 4; i++) {
                int f = t + 256 * i;
                int r = f >> 3, c4 = (f & 7) * 4;
                float4 v = *(const float4*)(A + (size_t)(cb + m0 + r) * (NGRP * DMODEL)
                                              + (size_t)n * DMODEL + k0 + c4);
                bf16x4 p;
                p[0] = (short)f2bf(v.x); p[1] = (short)f2bf(v.y);
                p[2] = (short)f2bf(v.z); p[3] = (short)f2bf(v.w);
                *(bf16x4*)&Al[r * LDP + c4] = p;
            }
        } else {
            const ushort* A = (const ushort*)Ap;
#pragma unroll
            for (int i = 0; i < 2; i++) {
                int c = t + 256 * i;
                int r = c >> 2, c8 = (c & 3) * 8;
                bf16x8 v = *(const bf16x8*)(A + ((size_t)n * CH + m0 + r) * HIDDEN + k0 + c8);
                *(bf16x8*)&Al[r * LDP + c8] = v;
            }
        }

        // ---- stage B tile transposed: Bl[col][k], XOR-swizzled k offset ----
        {
            float4 v[4];
#pragma unroll
            for (int i = 0; i < 4; i++)
                v[i] = *(const float4*)(Wg + (size_t)(k0 + kb * 4 + i) * NDIM + bn0 + nb * 4);
            const int swzW = ((nb >> 1) & 3) << 3;   // ((row>>3)&3)<<3 ; row = nb*4+j
#pragma unroll
            for (int j = 0; j < 4; j++) {
                bf16x4 p;
                p[0] = (short)f2bf(((const float*)&v[0])[j]);
                p[1] = (short)f2bf(((const float*)&v[1])[j]);
                p[2] = (short)f2bf(((const float*)&v[2])[j]);
                p[3] = (short)f2bf(((const float*)&v[3])[j]);
                *(bf16x4*)&Bl[(nb * 4 + j) * LDP + ((kb * 4) ^ swzW)] = p;
            }
        }
        __syncthreads();

        // ---- fragments + MFMA ----
        bf16x8 af[4], bfr[4];
#pragma unroll
        for (int m = 0; m < 4; m++) {
            const int rowA = wr * 64 + m * 16 + lr;
            af[m] = *(const bf16x8*)&Al[rowA * LDP + lq * 8];
        }
#pragma unroll
        for (int nf = 0; nf < 4; nf++) {
            const int rowB = wc * 64 + nf * 16 + lr;
            const int swzB = ((rowB >> 3) & 3) << 3;
            bfr[nf] = *(const bf16x8*)&Bl[rowB * LDP + ((lq * 8) ^ swzB)];
        }
#pragma unroll
        for (int m = 0; m < 4; m++)
#pragma unroll
            for (int nf = 0; nf < 4; nf++)
                acc[m][nf] = __builtin_amdgcn_mfma_f32_16x16x32_bf16(af[m], bfr[nf], acc[m][nf], 0, 0, 0);
    }

    // ---- epilogue: bias (+relu) and store ----
#pragma unroll
    for (int nf = 0; nf < 4; nf++) {
        const int colg = bn0 + wc * 64 + nf * 16 + lr;
        const float bias = biasp[(size_t)n * NDIM + colg];
#pragma unroll
        for (int m = 0; m < 4; m++) {
#pragma unroll
            for (int r = 0; r < 4; r++) {
                float vv = acc[m][nf][r] + bias;
                const int row = m0 + wr * 64 + m * 16 + lq * 4 + r;  // within chunk
                if constexpr (MODE == 0) {
                    vv = fmaxf(vv, 0.f);
                    ((ushort*)outp)[((size_t)n * CH + row) * HIDDEN + colg] = f2bf(vv);
                } else {
                    ((float*)outp)[(((size_t)(cb + row)) * NGRP + n) * ABIN + colg] = vv;
                }
            }
        }
    }
}

extern "C" void kernel_launch(void* const* d_in, const int* in_sizes, int n_in,
                              void* d_out, int out_size, void* d_ws, size_t ws_size,
                              hipStream_t stream)
{
    const float* x  = (const float*)d_in[0];
    const float* W1 = (const float*)d_in[1];
    const float* b1 = (const float*)d_in[2];
    const float* W2 = (const float*)d_in[3];
    const float* b2 = (const float*)d_in[4];
    float* out = (float*)d_out;

    // h chunk (bf16) lives in d_ws: NGRP * CH * HIDDEN * 2 bytes
    int CH = 4096;
    while (CH > 128 && (size_t)NGRP * (size_t)CH * HIDDEN * 2 > ws_size) CH >>= 1;

    for (int cb = 0; cb < BTOT; cb += CH) {
        dim3 g1((CH / 128) * (HIDDEN / 128), NGRP);
        mlp_gemm<0><<<g1, 256, 0, stream>>>(x, W1, b1, d_ws, CH, cb);
        dim3 g2((CH / 128) * (ABIN / 128), NGRP);
        mlp_gemm<1><<<g2, 256, 0, stream>>>(d_ws, W2, b2, out, CH, cb);
    }
}

// Round 2
// 288.767 us; speedup vs baseline: 2.3752x; 2.3752x over previous
//
#include <hip/hip_runtime.h>
#include <stdint.h>

#define BTOT   4096
#define NGRP   8
#define DMODEL 1024
#define HIDDEN 2048
#define ABIN   256

typedef short bf16x8 __attribute__((ext_vector_type(8)));
typedef float f32x4  __attribute__((ext_vector_type(4)));

__device__ __forceinline__ ushort f2bf(float f) {
    union { float f; uint32_t u; } v; v.f = f;
    return (ushort)((v.u + 0x7FFFu + ((v.u >> 16) & 1u)) >> 16);
}

__device__ __forceinline__ void gl_lds16(const ushort* g, ushort* l) {
    __builtin_amdgcn_global_load_lds(
        (const __attribute__((address_space(1))) uint32_t*)g,
        (__attribute__((address_space(3))) uint32_t*)l,
        16, 0, 0);
}

// ---- W[n][K][N] f32  ->  Wt[n][N][K] bf16 (B^T layout for the GEMM) ----
__global__ void transpose_w(const float* __restrict__ W, ushort* __restrict__ Wt,
                            int K, int N)
{
    __shared__ float tl[32][33];
    const int n  = blockIdx.y;
    const int nt = blockIdx.x % (N / 32);
    const int kt = blockIdx.x / (N / 32);
    const float* Wn  = W  + (size_t)n * K * N;
    ushort*      Wtn = Wt + (size_t)n * N * K;
    const int tx = threadIdx.x & 31, ty = threadIdx.x >> 5;   // 32 x 8
#pragma unroll
    for (int j = 0; j < 4; j++)
        tl[ty + 8 * j][tx] = Wn[(size_t)(kt * 32 + ty + 8 * j) * N + nt * 32 + tx];
    __syncthreads();
#pragma unroll
    for (int j = 0; j < 4; j++) {
        const int r = ty + 8 * j;   // N index within tile
        Wtn[(size_t)(nt * 32 + r) * K + kt * 32 + tx] = f2bf(tl[tx][r]);
    }
}

// ---- x[cb+r][n][d] f32 -> xb[n][r][d] bf16 (per chunk) ----
__global__ void conv_x(const float* __restrict__ x, ushort* __restrict__ xb,
                       int CH, int cb)
{
    const int flat = blockIdx.x * 256 + threadIdx.x;    // CH*1024 threads, 8 elems each
    const int d8 = flat & 127;
    const int rem = flat >> 7;
    const int n = rem & 7;
    const int r = rem >> 3;
    const float* src = x + ((size_t)(cb + r) * NGRP + n) * DMODEL + d8 * 8;
    float4 v0 = *(const float4*)(src);
    float4 v1 = *(const float4*)(src + 4);
    bf16x8 p;
    p[0] = (short)f2bf(v0.x); p[1] = (short)f2bf(v0.y);
    p[2] = (short)f2bf(v0.z); p[3] = (short)f2bf(v0.w);
    p[4] = (short)f2bf(v1.x); p[5] = (short)f2bf(v1.y);
    p[6] = (short)f2bf(v1.z); p[7] = (short)f2bf(v1.w);
    *(bf16x8*)(xb + ((size_t)n * CH + r) * DMODEL + d8 * 8) = p;
}

// ---- m97-structure GEMM:  A[M][K] bf16  x  Bt[N][K] bf16 ----
// MODE 0: K=1024, N=2048, out = relu(.)+b1 -> h bf16 [n][CH][HIDDEN]
// MODE 1: K=2048, N=256,  out = .+b2       -> f32 [b][n][ABIN]
template<int MODE>
__global__ __launch_bounds__(256, 2)
void gemm_bt(const ushort* __restrict__ A, const ushort* __restrict__ Bt,
             const float* __restrict__ bias, void* __restrict__ outp,
             int CH, int cb)
{
    constexpr int K    = (MODE == 0) ? DMODEL : HIDDEN;
    constexpr int NDIM = (MODE == 0) ? HIDDEN : ABIN;
    constexpr int NT   = NDIM / 128;
    constexpr int BK   = 64;

    __shared__ __align__(16) ushort As[128 * BK];
    __shared__ __align__(16) ushort Bs[128 * BK];

    const int n  = blockIdx.y;
    const int mt = blockIdx.x / NT;
    const int nt = blockIdx.x % NT;

    const ushort* Ab = A  + ((size_t)n * CH   + mt * 128) * K;
    const ushort* Bb = Bt + ((size_t)n * NDIM + nt * 128) * K;

    const int t = threadIdx.x, l = t & 63, w = t >> 6;
    const int wr = w >> 1, wc = w & 1;
    const int lq = l >> 4, lr = l & 15;

    f32x4 acc[4][4];
#pragma unroll
    for (int i = 0; i < 4; i++)
#pragma unroll
        for (int j = 0; j < 4; j++) acc[i][j] = (f32x4){0.f, 0.f, 0.f, 0.f};

    for (int ki = 0; ki < K / BK; ++ki) {
        const ushort* Ak = Ab + ki * BK;
        const ushort* Bk = Bb + ki * BK;
        __syncthreads();
#pragma unroll
        for (int i = 0; i < 4; i++) {
            const int flat = t + 256 * i;
            const int row = flat >> 3, seg = flat & 7;
            gl_lds16(Ak + (size_t)row * K + seg * 8, (ushort*)As + flat * 8);
            gl_lds16(Bk + (size_t)row * K + seg * 8, (ushort*)Bs + flat * 8);
        }
        __syncthreads();   // drains vmcnt(0): staged data visible

#pragma unroll
        for (int kk = 0; kk < 2; kk++) {
            bf16x8 af[4], bf[4];
#pragma unroll
            for (int m = 0; m < 4; m++)
                af[m] = *(const bf16x8*)&As[(wr * 64 + m * 16 + lr) * BK + kk * 32 + lq * 8];
#pragma unroll
            for (int nf = 0; nf < 4; nf++)
                bf[nf] = *(const bf16x8*)&Bs[(wc * 64 + nf * 16 + lr) * BK + kk * 32 + lq * 8];
#pragma unroll
            for (int m = 0; m < 4; m++)
#pragma unroll
                for (int nf = 0; nf < 4; nf++)
                    acc[m][nf] = __builtin_amdgcn_mfma_f32_16x16x32_bf16(af[m], bf[nf], acc[m][nf], 0, 0, 0);
        }
    }

    // ---- epilogue ----
#pragma unroll
    for (int nf = 0; nf < 4; nf++) {
        const int colg = nt * 128 + wc * 64 + nf * 16 + lr;
        const float bv = bias[(size_t)n * NDIM + colg];
#pragma unroll
        for (int m = 0; m < 4; m++) {
#pragma unroll
            for (int r = 0; r < 4; r++) {
                float vv = acc[m][nf][r] + bv;
                const int row = mt * 128 + wr * 64 + m * 16 + lq * 4 + r;  // within chunk
                if constexpr (MODE == 0) {
                    vv = fmaxf(vv, 0.f);
                    ((ushort*)outp)[((size_t)n * CH + row) * HIDDEN + colg] = f2bf(vv);
                } else {
                    ((float*)outp)[((size_t)(cb + row) * NGRP + n) * ABIN + colg] = vv;
                }
            }
        }
    }
}

extern "C" void kernel_launch(void* const* d_in, const int* in_sizes, int n_in,
                              void* d_out, int out_size, void* d_ws, size_t ws_size,
                              hipStream_t stream)
{
    const float* x  = (const float*)d_in[0];
    const float* W1 = (const float*)d_in[1];
    const float* b1 = (const float*)d_in[2];
    const float* W2 = (const float*)d_in[3];
    const float* b2 = (const float*)d_in[4];

    // workspace layout (bf16): W1t [8][2048][1024] | W2t [8][256][2048]
    //                          | xb [8][CH][1024]  | h [8][CH][2048]
    ushort* W1t = (ushort*)d_ws;                              // 32 MiB
    ushort* W2t = W1t + (size_t)NGRP * HIDDEN * DMODEL;       //  8 MiB
    ushort* xb  = W2t + (size_t)NGRP * ABIN * HIDDEN;
    const size_t fixed = ((size_t)NGRP * HIDDEN * DMODEL + (size_t)NGRP * ABIN * HIDDEN) * 2;

    int CH = 4096;
    while (CH > 128 && fixed + (size_t)CH * (NGRP * (DMODEL + HIDDEN) * 2) > ws_size) CH >>= 1;
    ushort* h = xb + (size_t)NGRP * CH * DMODEL;

    // one-time weight transpose+convert
    {
        dim3 g1((DMODEL / 32) * (HIDDEN / 32), NGRP);
        transpose_w<<<g1, 256, 0, stream>>>(W1, W1t, DMODEL, HIDDEN);
        dim3 g2((HIDDEN / 32) * (ABIN / 32), NGRP);
        transpose_w<<<g2, 256, 0, stream>>>(W2, W2t, HIDDEN, ABIN);
    }

    for (int cb = 0; cb < BTOT; cb += CH) {
        conv_x<<<CH * 4, 256, 0, stream>>>(x, xb, CH, cb);
        dim3 g1((CH / 128) * (HIDDEN / 128), NGRP);
        gemm_bt<0><<<g1, 256, 0, stream>>>(xb, W1t, b1, h, CH, cb);
        dim3 g2((CH / 128) * (ABIN / 128), NGRP);
        gemm_bt<1><<<g2, 256, 0, stream>>>(h, W2t, b2, (float*)d_out, CH, cb);
    }
}